// Round 1
// 519.056 us; speedup vs baseline: 1.0012x; 1.0012x over previous
//
#include <hip/hip_runtime.h>

// Problem constants (fixed by the reference setup_inputs)
constexpr int B  = 8;
constexpr int D  = 64;
constexpr int H  = 384;
constexpr int W  = 512;
constexpr int HW  = H * W;            // 196608 pixels per (b,d) plane
constexpr int NP  = B * HW;           // 1572864 pixels
constexpr int NP4 = NP / 4;           // 393216 pixel-quads (float4 granularity)
constexpr int TPB    = 256;
constexpr int BLOCKS = NP4 / TPB;     // 1536 blocks -> exactly 6 blocks/CU
constexpr float INV_SPLITS = 1.0f / 6.0f;

// Pixel-major, 4 pixels/thread via float4: each wave load covers 1 KiB
// contiguous (the 16 B/lane coalescing sweet spot), each block 4 KiB per
// d-step. Running diff (exact: gr is integer-valued after rintf, and
// inf - 1 = inf) removes the per-iteration int->float convert. Four
// independent per-pixel accumulators; the {0,1} mask is applied once at
// the end (exact).
__global__ __launch_bounds__(TPB, 6)
void sce_main(const float* __restrict__ sim,
              const float* __restrict__ gt,
              float*       __restrict__ psum,
              float*       __restrict__ pcnt) {
    const int tid = blockIdx.x * TPB + threadIdx.x;
    const int p   = tid * 4;                    // first pixel of the quad
    const int b   = (unsigned)p / (unsigned)HW; // magic-mul, once per thread
    const int pp  = p - b * HW;                 // offset within plane (mult of 4)

    const float4 g = *reinterpret_cast<const float4*>(gt + p);

    // round(gt/2): rintf = round-half-even, matches jnp.round. inf stays inf:
    // diff stays inf through decrements -> r = max(6 - inf, 0) = 0 -> P = 0,
    // so the unknown-pixel accumulator holds sum|s| and is zeroed by m=0.
    float d0 = rintf(g.x * 0.5f);
    float d1 = rintf(g.y * 0.5f);
    float d2 = rintf(g.z * 0.5f);
    float d3 = rintf(g.w * 0.5f);
    const float m0 = isinf(g.x) ? 0.0f : 1.0f;
    const float m1 = isinf(g.y) ? 0.0f : 1.0f;
    const float m2 = isinf(g.z) ? 0.0f : 1.0f;
    const float m3 = isinf(g.w) ? 0.0f : 1.0f;

    const float* sp = sim + (size_t)b * D * HW + pp;

    float a0 = 0.0f, a1 = 0.0f, a2 = 0.0f, a3 = 0.0f;
    #pragma unroll 8
    for (int d = 0; d < D; ++d) {
        const float4 s = *reinterpret_cast<const float4*>(sp + (size_t)d * HW);
        // P = max(0, 6 - |gr - d|) / 6 ; term = |s - P|
        const float r0 = fmaxf(6.0f - fabsf(d0), 0.0f);
        const float r1 = fmaxf(6.0f - fabsf(d1), 0.0f);
        const float r2 = fmaxf(6.0f - fabsf(d2), 0.0f);
        const float r3 = fmaxf(6.0f - fabsf(d3), 0.0f);
        a0 += fabsf(fmaf(r0, INV_SPLITS, -s.x));
        a1 += fabsf(fmaf(r1, INV_SPLITS, -s.y));
        a2 += fabsf(fmaf(r2, INV_SPLITS, -s.z));
        a3 += fabsf(fmaf(r3, INV_SPLITS, -s.w));
        d0 -= 1.0f; d1 -= 1.0f; d2 -= 1.0f; d3 -= 1.0f;
    }

    float acc = fmaf(a0, m0, fmaf(a1, m1, fmaf(a2, m2, a3 * m3)));
    float cnt = (m0 + m1) + (m2 + m3);

    // ---- block reduction: wave64 shuffle -> LDS across 4 waves ----
    #pragma unroll
    for (int off = 32; off > 0; off >>= 1) {
        acc += __shfl_down(acc, off, 64);
        cnt += __shfl_down(cnt, off, 64);
    }

    __shared__ float s_sum[4];
    __shared__ float s_cnt[4];
    const int wave = threadIdx.x >> 6;
    const int lane = threadIdx.x & 63;
    if (lane == 0) { s_sum[wave] = acc; s_cnt[wave] = cnt; }
    __syncthreads();
    if (threadIdx.x == 0) {
        psum[blockIdx.x] = (s_sum[0] + s_sum[1]) + (s_sum[2] + s_sum[3]);
        pcnt[blockIdx.x] = (s_cnt[0] + s_cnt[1]) + (s_cnt[2] + s_cnt[3]);
    }
}

// Single-block reducer over the per-block partials (double accumulate).
__global__ __launch_bounds__(TPB)
void sce_final(const float* __restrict__ psum,
               const float* __restrict__ pcnt,
               float*       __restrict__ out) {
    double a = 0.0;
    double c = 0.0;
    for (int i = threadIdx.x; i < BLOCKS; i += TPB) {
        a += (double)psum[i];
        c += (double)pcnt[i];
    }
    #pragma unroll
    for (int off = 32; off > 0; off >>= 1) {
        a += __shfl_down(a, off, 64);
        c += __shfl_down(c, off, 64);
    }
    __shared__ double s_a[4];
    __shared__ double s_c[4];
    const int wave = threadIdx.x >> 6;
    const int lane = threadIdx.x & 63;
    if (lane == 0) { s_a[wave] = a; s_c[wave] = c; }
    __syncthreads();
    if (threadIdx.x == 0) {
        double ta = (s_a[0] + s_a[1]) + (s_a[2] + s_a[3]);
        double tc = (s_c[0] + s_c[1]) + (s_c[2] + s_c[3]);
        out[0] = (float)(ta / (tc * (double)D));
    }
}

extern "C" void kernel_launch(void* const* d_in, const int* in_sizes, int n_in,
                              void* d_out, int out_size, void* d_ws, size_t ws_size,
                              hipStream_t stream) {
    const float* sim = (const float*)d_in[0];
    const float* gt  = (const float*)d_in[1];
    float* out = (float*)d_out;

    float* psum = (float*)d_ws;
    float* pcnt = (float*)((char*)d_ws + BLOCKS * sizeof(float));

    sce_main<<<BLOCKS, TPB, 0, stream>>>(sim, gt, psum, pcnt);
    sce_final<<<1, TPB, 0, stream>>>(psum, pcnt, out);
}